// Round 6
// baseline (665.190 us; speedup 1.0000x reference)
//
#include <hip/hip_runtime.h>
#include <hip/hip_bf16.h>

#define B_   2
#define S_   2048
#define H_   2048
#define D_   256
#define NH_  8

typedef unsigned short u16;
typedef __bf16 bf16x8 __attribute__((ext_vector_type(8)));
typedef float f32x4 __attribute__((ext_vector_type(4)));
typedef unsigned int uint4v __attribute__((ext_vector_type(4)));
typedef unsigned int uint2v __attribute__((ext_vector_type(2)));

#define AS1 __attribute__((address_space(1)))
#define AS3 __attribute__((address_space(3)))

__device__ __forceinline__ u16 f2bf(float x) {
  union { float f; unsigned u; } v; v.f = x;
  unsigned u = v.u;
  u += 0x7FFFu + ((u >> 16) & 1u);   // round-to-nearest-even
  return (u16)(u >> 16);
}
__device__ __forceinline__ float bf2f(u16 x) {
  union { unsigned u; float f; } v; v.u = ((unsigned)x) << 16;
  return v.f;
}

__device__ __forceinline__ void bf8_unpack(uint4v u, float* f) {
  f[0] = bf2f(u.x & 0xffff); f[1] = bf2f(u.x >> 16);
  f[2] = bf2f(u.y & 0xffff); f[3] = bf2f(u.y >> 16);
  f[4] = bf2f(u.z & 0xffff); f[5] = bf2f(u.z >> 16);
  f[6] = bf2f(u.w & 0xffff); f[7] = bf2f(u.w >> 16);
}
__device__ __forceinline__ uint4v bf8_pack(const float* f) {
  uint4v o;
  o.x = (unsigned)f2bf(f[0]) | ((unsigned)f2bf(f[1]) << 16);
  o.y = (unsigned)f2bf(f[2]) | ((unsigned)f2bf(f[3]) << 16);
  o.z = (unsigned)f2bf(f[4]) | ((unsigned)f2bf(f[5]) << 16);
  o.w = (unsigned)f2bf(f[6]) | ((unsigned)f2bf(f[7]) << 16);
  return o;
}

// async 16B global -> LDS (m97 pattern; LDS dest must be wave-uniform base + lane*16)
__device__ __forceinline__ void gld_lds16(const u16* g, u16* l) {
  __builtin_amdgcn_global_load_lds((const AS1 unsigned int*)g,
                                   (AS3 unsigned int*)l, 16, 0, 0);
}

// ---------------------------------------------------------------------------
// Tiled NT GEMM: C[M,N] = A[M,K] * B[N,K]^T, bf16 MFMA 16x16x32, fp32 acc.
// BM=BN=128, BK=64 (halves barrier-drain events vs BK=32 — the dominant
// 2-phase cost per m233), 256 thr = 4 waves 2x2, wave does 64x64 (4x4 MFMA).
// Staging via global_load_lds dwordx4, unpadded LDS.  LDS 33 KB; occupancy
// stays VGPR-limited (~3 blocks/CU), unlike BK=128 (m132 regression).
// bf16 epilogues repack through LDS -> 16B/lane stores; WO repacks to float4.
// QK: triangular grid.  PV: bm reversed (longest K first) + fused P-write:
// bn==0 converts the staged E tile (As) to fp32 * inv(rowsum) during the
// K-loop (E read from LDS = free; proven better than streaming re-read, R5).
// ---------------------------------------------------------------------------
#define BM 128
#define BN 128
#define BK 64

enum GemmMode { MODE_PROJ = 0, MODE_QK = 1, MODE_PV = 2, MODE_WO = 3 };

template <int MODE>
__global__ __launch_bounds__(256)
void gemm_nt(const u16* __restrict__ A, const u16* __restrict__ Bb,
             void* __restrict__ Cp, float* __restrict__ rows,
             float* __restrict__ Pout,
             int K, int lda, int ldb, int ldc)
{
  int bn, bm;
  if constexpr (MODE == MODE_QK) {
    // triangular decode: blockIdx.x = bm*(bm+1)/2 + bn, bn <= bm
    int t = blockIdx.x;
    bm = 0;
    while ((bm + 1) * (bm + 2) / 2 <= t) bm++;
    bn = t - bm * (bm + 1) / 2;
  } else if constexpr (MODE == MODE_PV) {
    bn = blockIdx.x;
    bm = (int)gridDim.y - 1 - (int)blockIdx.y;   // longest K-loops dispatch first
  } else {
    bn = blockIdx.x;
    bm = blockIdx.y;
  }
  const int bz = blockIdx.z;
  const int m0 = bm * BM, n0 = bn * BN;
  const int tid = threadIdx.x;

  const u16* Ap = A;
  const u16* Bp = Bb;
  float* Cf = (float*)Cp;
  u16*   Cu = (u16*)Cp;
  float* Pp = Pout;

  if constexpr (MODE == MODE_QK) {
    Ap   += (size_t)bz * S_ * D_;           // Q slab (b,h)
    Bp   += (size_t)(bz >> 3) * S_ * D_;    // K slab (b)
    Cu   += (size_t)bz * S_ * S_;           // E slab (bf16, unnormalized exp)
    rows += (size_t)bz * S_;
  } else if constexpr (MODE == MODE_PV) {
    Ap   += (size_t)bz * S_ * S_;           // E slab (bf16)
    Bp   += (size_t)(bz >> 3) * D_ * S_;    // V^T slab (b)
    Cu   += (size_t)(bz >> 3) * S_ * (NH_ * D_) + (size_t)(bz & 7) * D_;
    rows += (size_t)bz * S_;
    Pp   += (size_t)bz * S_ * S_;           // P slab (fp32 attn_weights)
  }

  int Keff = K;
  if constexpr (MODE == MODE_PV) {          // E[m][k]==0 for k>m
    int lim = (bm + 1) * BM;
    Keff = lim < K ? lim : K;
  }

  // one shared pool: K-loop uses As|Bs; epilogue reuses it as Cs / Cs32
  __shared__ __align__(16) u16 smem[BM * BK + BN * BK + 512];
  u16* As = smem;
  u16* Bs = smem + BM * BK;
  __shared__ float invs[BM];                // PV: 1/rowsum for this row band

  const int lane = tid & 63;
  const int quad = lane >> 4;
  const int l16  = lane & 15;
  const int wave = tid >> 6;
  const int wm   = (wave >> 1) << 6;
  const int wn   = (wave & 1) << 6;

  if constexpr (MODE == MODE_PV) {
    if (tid < BM) invs[tid] = 1.0f / rows[m0 + tid];
  }

  f32x4 acc[4][4] = {};

  for (int kt = 0; kt < Keff; kt += BK) {
    // stage A,B tiles: 128 rows x 64 cols bf16 = 16 KB each; 8x 16B chunks/row
    #pragma unroll
    for (int i = 0; i < 4; i++) {
      int c = tid + i * 256;                // chunk id; lanes consecutive in LDS
      gld_lds16(Ap + (size_t)(m0 + (c >> 3)) * lda + kt + (c & 7) * 8, &As[c * 8]);
    }
    #pragma unroll
    for (int i = 0; i < 4; i++) {
      int c = tid + i * 256;
      gld_lds16(Bp + (size_t)(n0 + (c >> 3)) * ldb + kt + (c & 7) * 8, &Bs[c * 8]);
    }
    __syncthreads();                        // compiler drains vmcnt before barrier

    #pragma unroll
    for (int kk = 0; kk < 2; kk++) {
      bf16x8 af[4], bfr[4];
      #pragma unroll
      for (int i = 0; i < 4; i++)
        af[i] = *(const bf16x8*)(&As[(wm + i * 16 + l16) * BK + kk * 32 + quad * 8]);
      #pragma unroll
      for (int j = 0; j < 4; j++)
        bfr[j] = *(const bf16x8*)(&Bs[(wn + j * 16 + l16) * BK + kk * 32 + quad * 8]);
      #pragma unroll
      for (int i = 0; i < 4; i++)
        #pragma unroll
        for (int j = 0; j < 4; j++)
          acc[i][j] = __builtin_amdgcn_mfma_f32_16x16x32_bf16(af[i], bfr[j], acc[i][j], 0, 0, 0);
    }

    if constexpr (MODE == MODE_PV) {
      // fused P-write: P[m][kt..kt+64) = bf2f(E_tile) * inv(rowsum[m]) (fp32)
      if (bn == 0) {
        const int pr4 = tid >> 4;           // 0..15
        const int pc4 = (tid & 15) * 4;     // col 0..60 step 4
        #pragma unroll
        for (int rr = 0; rr < BM; rr += 16) {
          const int r = rr + pr4;
          const u16* e = &As[r * BK + pc4];
          const float inv = invs[r];
          float4 o;
          o.x = bf2f(e[0]) * inv; o.y = bf2f(e[1]) * inv;
          o.z = bf2f(e[2]) * inv; o.w = bf2f(e[3]) * inv;
          *(float4*)(Pp + (size_t)(m0 + r) * S_ + kt + pc4) = o;
        }
      }
    }
    __syncthreads();
  }

  if constexpr (MODE == MODE_PV) {
    // above-diagonal zeros: cols [Keff, S_) of this row band
    if (bn == 0 && Keff < S_) {
      const int r8 = tid >> 3;
      const int c8 = tid & 7;
      const float4 z = {0.f, 0.f, 0.f, 0.f};
      #pragma unroll
      for (int rr = 0; rr < BM; rr += 32) {
        float* pr = Pp + (size_t)(m0 + rr + r8) * S_;
        for (int c4 = (Keff >> 2) + c8; c4 < (S_ >> 2); c4 += 8)
          *(float4*)(pr + c4 * 4) = z;
      }
    }
  }

  // ---- epilogue ----
  const float SCL2 = 0.0625f * 1.44269504088896340736f;  // D^-0.5 * log2(e)
  if constexpr (MODE == MODE_WO) {
    // fp32 output: LDS repack -> float4 coalesced stores. 32 rows x 132 floats.
    float (*Cs32)[132] = (float (*)[132])smem;
    const int band16 = (wave >> 1) * 16;
    #pragma unroll
    for (int i = 0; i < 4; i++) {
      #pragma unroll
      for (int r = 0; r < 4; r++) {
        const int lr = band16 + quad * 4 + r;
        #pragma unroll
        for (int j = 0; j < 4; j++)
          Cs32[lr][wn + j * 16 + l16] = acc[i][j][r];
      }
      __syncthreads();
      #pragma unroll
      for (int ch = tid; ch < 1024; ch += 256) {
        const int rr = ch >> 5, cc = ch & 31;
        const int mg = m0 + ((rr >> 4) << 6) + i * 16 + (rr & 15);
        *(float4*)(Cf + (size_t)mg * ldc + n0 + cc * 4) =
            *(const float4*)(&Cs32[rr][cc * 4]);
      }
      __syncthreads();
    }
  } else {
    // bf16 outputs: LDS repack -> 16B/lane coalesced stores.
    u16 (*Cs)[136] = (u16 (*)[136])smem;
    const int band16 = (wave >> 1) * 16;
    #pragma unroll
    for (int i = 0; i < 4; i++) {
      #pragma unroll
      for (int r = 0; r < 4; r++) {
        const int lr = band16 + quad * 4 + r;
        const int m  = m0 + wm + i * 16 + quad * 4 + r;
        if constexpr (MODE == MODE_QK) {
          float rs = 0.f;
          #pragma unroll
          for (int j = 0; j < 4; j++) {
            int n = n0 + wn + j * 16 + l16;
            float e = (n <= m) ? exp2f(acc[i][j][r] * SCL2) : 0.f;
            rs += e;
            Cs[lr][wn + j * 16 + l16] = f2bf(e);
          }
          #pragma unroll
          for (int o = 1; o < 16; o <<= 1) rs += __shfl_xor(rs, o, 64);
          if (l16 == 0) atomicAdd(&rows[m], rs);
        } else if constexpr (MODE == MODE_PV) {
          const float inv = invs[wm + i * 16 + quad * 4 + r];
          #pragma unroll
          for (int j = 0; j < 4; j++)
            Cs[lr][wn + j * 16 + l16] = f2bf(acc[i][j][r] * inv);
        } else {
          #pragma unroll
          for (int j = 0; j < 4; j++)
            Cs[lr][wn + j * 16 + l16] = f2bf(acc[i][j][r]);
        }
      }
      __syncthreads();
      #pragma unroll
      for (int ch = tid; ch < 512; ch += 256) {
        const int rr = ch >> 4, cc = ch & 15;
        const int mg = m0 + ((rr >> 4) << 6) + i * 16 + (rr & 15);
        *(uint4v*)(Cu + (size_t)mg * ldc + n0 + cc * 8) =
            *(const uint4v*)(&Cs[rr][cc * 8]);
      }
      __syncthreads();
    }
  }
}

// ---------------------------------------------------------------------------
// Merged prep: 4x transpose_convert (Wq|Wk|Wv -> WT packed, Wo -> WoT) +
// X fp32 -> bf16 convert + Rows zero-fill.  Flat block decode.
// ---------------------------------------------------------------------------
__device__ __forceinline__ void tc_tile(const float* __restrict__ src,
                                        u16* __restrict__ dst, int K, int N,
                                        int n0, int k0, float (*t)[33])
{
  int c = threadIdx.x & 31, r = threadIdx.x >> 5;
  #pragma unroll
  for (int rr = 0; rr < 32; rr += 8)
    t[r + rr][c] = src[(size_t)(k0 + r + rr) * N + n0 + c];
  __syncthreads();
  #pragma unroll
  for (int rr = 0; rr < 32; rr += 8)
    dst[(size_t)(n0 + r + rr) * K + k0 + c] = f2bf(t[c][r + rr]);
}

__global__ __launch_bounds__(256)
void prep_kernel(const float* __restrict__ X,
                 const float* __restrict__ Wq, const float* __restrict__ Wk,
                 const float* __restrict__ Wv, const float* __restrict__ Wo,
                 u16* __restrict__ Xbf, u16* __restrict__ WT,
                 u16* __restrict__ WoT, float* __restrict__ Rows)
{
  __shared__ float t[32][33];
  const int bid = blockIdx.x;
  if (bid < 4096) {                                   // Wq: 64x64 tiles
    tc_tile(Wq, WT, 2048, 2048, (bid & 63) * 32, (bid >> 6) * 32, t);
  } else if (bid < 4608) {                            // Wk: 8x64 tiles
    int l = bid - 4096;
    tc_tile(Wk, WT + 2048 * 2048, 2048, 256, (l & 7) * 32, (l >> 3) * 32, t);
  } else if (bid < 5120) {                            // Wv: 8x64 tiles
    int l = bid - 4608;
    tc_tile(Wv, WT + 2304 * 2048, 2048, 256, (l & 7) * 32, (l >> 3) * 32, t);
  } else if (bid < 9216) {                            // Wo: 64x64 tiles
    int l = bid - 5120;
    tc_tile(Wo, WoT, 2048, 2048, (l & 63) * 32, (l >> 6) * 32, t);
  } else if (bid < 11264) {                           // X fp32 -> bf16
    int l = bid - 9216;                               // 0..2047
    #pragma unroll
    for (int it = 0; it < 4; ++it) {
      int i = it * 524288 + l * 256 + threadIdx.x;
      float4 f = ((const float4*)X)[i];
      uint2v p;
      p.x = (unsigned)f2bf(f.x) | ((unsigned)f2bf(f.y) << 16);
      p.y = (unsigned)f2bf(f.z) | ((unsigned)f2bf(f.w) << 16);
      ((uint2v*)Xbf)[i] = p;
    }
  } else {                                            // zero Rows (8 blocks)
    int l = bid - 11264;
    const float4 z = {0.f, 0.f, 0.f, 0.f};
    #pragma unroll
    for (int it = 0; it < 4; ++it)
      ((float4*)Rows)[it * 2048 + l * 256 + threadIdx.x] = z;
  }
}

// ---------------------------------------------------------------------------
// Merged post-projection: RoPE-Q, RoPE-K (16B vectorized), V-transpose.
// RoPE handles (d, d+128) pairs; cos[d+128]==cos[d] (emb = concat(freqs,freqs)).
// ---------------------------------------------------------------------------
__global__ __launch_bounds__(256)
void postproj_kernel(const u16* __restrict__ raw, const float* __restrict__ cosb,
                     const float* __restrict__ sinb, u16* __restrict__ qout,
                     u16* __restrict__ kout, u16* __restrict__ vt)
{
  __shared__ u16 t[32][34];
  const int bid = blockIdx.x;
  if (bid < 1024) {                                   // RoPE Q (vectorized)
    const int row = threadIdx.x >> 4;                 // 0..15
    const int d8  = (threadIdx.x & 15) * 8;           // 0..120
    #pragma unroll
    for (int it2 = 0; it2 < 2; ++it2) {
      int idx = bid * 32 + it2 * 16 + row;            // (bs*NH + h) in [0, 32768)
      int h = idx & 7, bs = idx >> 3;
      int b = bs >> 11, s = bs & (S_ - 1);
      size_t base = (size_t)bs * 2560 + (size_t)h * D_;
      uint4v u1 = *(const uint4v*)(raw + base + d8);
      uint4v u2 = *(const uint4v*)(raw + base + 128 + d8);
      float4 c0 = *(const float4*)(cosb + (size_t)bs * D_ + d8);
      float4 c1 = *(const float4*)(cosb + (size_t)bs * D_ + d8 + 4);
      float4 s0 = *(const float4*)(sinb + (size_t)bs * D_ + d8);
      float4 s1 = *(const float4*)(sinb + (size_t)bs * D_ + d8 + 4);
      float a[8], bq[8], cc[8], ss[8], r1[8], r2[8];
      bf8_unpack(u1, a); bf8_unpack(u2, bq);
      cc[0]=c0.x; cc[1]=c0.y; cc[2]=c0.z; cc[3]=c0.w;
      cc[4]=c1.x; cc[5]=c1.y; cc[6]=c1.z; cc[7]=c1.w;
      ss[0]=s0.x; ss[1]=s0.y; ss[2]=s0.z; ss[3]=s0.w;
      ss[4]=s1.x; ss[5]=s1.y; ss[6]=s1.z; ss[7]=s1.w;
      #pragma unroll
      for (int i = 0; i < 8; ++i) {
        r1[i] = a[i] * cc[i] - bq[i] * ss[i];
        r2[i] = bq[i] * cc[i] + a[i] * ss[i];
      }
      size_t ob = (((size_t)b * NH_ + h) * S_ + s) * D_;
      *(uint4v*)(qout + ob + d8)       = bf8_pack(r1);
      *(uint4v*)(qout + ob + 128 + d8) = bf8_pack(r2);
    }
  } else if (bid < 1280) {                            // RoPE K (vectorized)
    const int l   = bid - 1024;                       // 0..255
    const int row = threadIdx.x >> 4;                 // 0..15
    const int d8  = (threadIdx.x & 15) * 8;
    int bs = l * 16 + row;                            // in [0, 4096)
    size_t base = (size_t)bs * 2560 + 2048;
    uint4v u1 = *(const uint4v*)(raw + base + d8);
    uint4v u2 = *(const uint4v*)(raw + base + 128 + d8);
    float4 c0 = *(const float4*)(cosb + (size_t)bs * D_ + d8);
    float4 c1 = *(const float4*)(cosb + (size_t)bs * D_ + d8 + 4);
    float4 s0 = *(const float4*)(sinb + (size_t)bs * D_ + d8);
    float4 s1 = *(const float4*)(sinb + (size_t)bs * D_ + d8 + 4);
    float a[8], bq[8], cc[8], ss[8], r1[8], r2[8];
    bf8_unpack(u1, a); bf8_unpack(u2, bq);
    cc[0]=c0.x; cc[1]=c0.y; cc[2]=c0.z; cc[3]=c0.w;
    cc[4]=c1.x; cc[5]=c1.y; cc[6]=c1.z; cc[7]=c1.w;
    ss[0]=s0.x; ss[1]=s0.y; ss[2]=s0.z; ss[3]=s0.w;
    ss[4]=s1.x; ss[5]=s1.y; ss[6]=s1.z; ss[7]=s1.w;
    #pragma unroll
    for (int i = 0; i < 8; ++i) {
      r1[i] = a[i] * cc[i] - bq[i] * ss[i];
      r2[i] = bq[i] * cc[i] + a[i] * ss[i];
    }
    *(uint4v*)(kout + (size_t)bs * D_ + d8)       = bf8_pack(r1);
    *(uint4v*)(kout + (size_t)bs * D_ + 128 + d8) = bf8_pack(r2);
  } else {                                            // V transpose -> (B,D,S)
    int l = bid - 1280;                               // 0..1023
    int b = l >> 9, rem = l & 511;
    int d0 = (rem & 7) * 32, s0 = (rem >> 3) * 32;
    int c = threadIdx.x & 31, r = threadIdx.x >> 5;
    #pragma unroll
    for (int rr = 0; rr < 32; rr += 8)
      t[r + rr][c] = raw[(size_t)(b * S_ + s0 + r + rr) * 2560 + 2304 + d0 + c];
    __syncthreads();
    #pragma unroll
    for (int rr = 0; rr < 32; rr += 8)
      vt[(size_t)b * D_ * S_ + (size_t)(d0 + r + rr) * S_ + s0 + c] = t[c][r + rr];
  }
}

// ---------------------------------------------------------------------------
extern "C" void kernel_launch(void* const* d_in, const int* in_sizes, int n_in,
                              void* d_out, int out_size, void* d_ws, size_t ws_size,
                              hipStream_t stream)
{
  const float* X    = (const float*)d_in[0];
  const float* cosb = (const float*)d_in[1];
  const float* sinb = (const float*)d_in[2];
  // d_in[3] = attention_mask (pure causal; synthesized in-kernel)
  const float* Wq   = (const float*)d_in[4];
  const float* Wk   = (const float*)d_in[5];
  const float* Wv   = (const float*)d_in[6];
  const float* Wo   = (const float*)d_in[7];

  float* outO = (float*)d_out;                               // (B,S,H) fp32
  float* outP = outO + (size_t)B_ * S_ * H_;                 // (B,NH,S,S) fp32

  // workspace layout (u16 elems), no aliasing (~229 MB total)
  u16* ws     = (u16*)d_ws;
  u16* Xbf    = ws;                          //  8,388,608  X bf16 (B*S, H)
  u16* WT     = Xbf    + 8388608;            //  5,242,880  packed [Wq|Wk|Wv]^T (2560,2048)
  u16* WoT    = WT     + 5242880;            //  4,194,304  Wo^T (2048,2048)
  u16* QKVraw = WoT    + 4194304;            // 10,485,760  X@W (B*S, 2560)
  u16* Qbf    = QKVraw + 10485760;           //  8,388,608  (B,NH,S,D) post-RoPE
  u16* Kbf    = Qbf    + 8388608;            //  1,048,576  (B,S,D)   post-RoPE
  u16* VT     = Kbf    + 1048576;            //  1,048,576  (B,D,S)
  u16* AObf   = VT     + 1048576;            //  8,388,608  (B,S,NH*D)
  u16* Ebf    = AObf   + 8388608;            // 67,108,864  unnormalized exp (B,NH,S,S)
  float* Rows = (float*)(Ebf + 67108864);    //     32,768  fp32 row sums

  // 1. prep: X->bf16 + weight transposes + Rows zero (one dispatch)
  prep_kernel<<<11272, 256, 0, stream>>>(X, Wq, Wk, Wv, Wo, Xbf, WT, WoT, Rows);
  // 2. fused QKV projection (one GEMM, N=2560)
  gemm_nt<MODE_PROJ><<<dim3(20, 32, 1), 256, 0, stream>>>(
      Xbf, WT, QKVraw, nullptr, nullptr, 2048, 2048, 2048, 2560);
  // 3. RoPE Q/K + V transpose (one dispatch)
  postproj_kernel<<<2304, 256, 0, stream>>>(QKVraw, cosb, sinb, Qbf, Kbf, VT);
  // 4. E = exp(QK^T * scale) bf16 (lower-tri tiles only), rowsums via atomics
  gemm_nt<MODE_QK><<<dim3(136, 1, 16), 256, 0, stream>>>(
      Qbf, Kbf, Ebf, Rows, nullptr, 256, 256, 256, 2048);
  // 5. attn_out = (E @ V) * inv(rowsum) + fused P = E * inv(rowsum) (fp32)
  gemm_nt<MODE_PV><<<dim3(2, 16, 16), 256, 0, stream>>>(
      Ebf, VT, AObf, Rows, outP, 2048, 2048, 2048, 2048);
  // 6. @ Wo -> fp32 attn_output
  gemm_nt<MODE_WO><<<dim3(16, 32, 1), 256, 0, stream>>>(
      AObf, WoT, outO, nullptr, nullptr, 2048, 2048, 2048, 2048);
}

// Round 7
// 637.472 us; speedup vs baseline: 1.0435x; 1.0435x over previous
//
#include <hip/hip_runtime.h>
#include <hip/hip_bf16.h>

#define B_   2
#define S_   2048
#define H_   2048
#define D_   256
#define NH_  8

typedef unsigned short u16;
typedef __bf16 bf16x8 __attribute__((ext_vector_type(8)));
typedef float f32x4 __attribute__((ext_vector_type(4)));
typedef unsigned int uint4v __attribute__((ext_vector_type(4)));
typedef unsigned int uint2v __attribute__((ext_vector_type(2)));

#define AS1 __attribute__((address_space(1)))
#define AS3 __attribute__((address_space(3)))

__device__ __forceinline__ u16 f2bf(float x) {
  union { float f; unsigned u; } v; v.f = x;
  unsigned u = v.u;
  u += 0x7FFFu + ((u >> 16) & 1u);   // round-to-nearest-even
  return (u16)(u >> 16);
}
__device__ __forceinline__ float bf2f(u16 x) {
  union { unsigned u; float f; } v; v.u = ((unsigned)x) << 16;
  return v.f;
}

__device__ __forceinline__ void bf8_unpack(uint4v u, float* f) {
  f[0] = bf2f(u.x & 0xffff); f[1] = bf2f(u.x >> 16);
  f[2] = bf2f(u.y & 0xffff); f[3] = bf2f(u.y >> 16);
  f[4] = bf2f(u.z & 0xffff); f[5] = bf2f(u.z >> 16);
  f[6] = bf2f(u.w & 0xffff); f[7] = bf2f(u.w >> 16);
}
__device__ __forceinline__ uint4v bf8_pack(const float* f) {
  uint4v o;
  o.x = (unsigned)f2bf(f[0]) | ((unsigned)f2bf(f[1]) << 16);
  o.y = (unsigned)f2bf(f[2]) | ((unsigned)f2bf(f[3]) << 16);
  o.z = (unsigned)f2bf(f[4]) | ((unsigned)f2bf(f[5]) << 16);
  o.w = (unsigned)f2bf(f[6]) | ((unsigned)f2bf(f[7]) << 16);
  return o;
}

// async 16B global -> LDS (m97 pattern; LDS dest must be wave-uniform base + lane*16)
__device__ __forceinline__ void gld_lds16(const u16* g, u16* l) {
  __builtin_amdgcn_global_load_lds((const AS1 unsigned int*)g,
                                   (AS3 unsigned int*)l, 16, 0, 0);
}

// ---------------------------------------------------------------------------
// Tiled NT GEMM: C[M,N] = A[M,K] * B[N,K]^T, bf16 MFMA 16x16x32, fp32 acc.
// BM=BN=128, BK=32 (R3-proven; BK=64 regressed in R6), 256 thr = 4 waves 2x2.
// Staging via global_load_lds dwordx4, unpadded LDS (m97: 874 TF recipe).
// bf16 epilogues repack through LDS -> 16B/lane stores; WO repacks to float4.
// PROJ/WO: 1D grid with bijective XCD swizzle (T1) — each XCD works a
// contiguous bm-chunk; A row-panels (2 MB) L2-resident per XCD.
// QK: triangular grid.  PV: bm reversed (longest K first) + fused P-write
// (bn==0 converts staged E tile from LDS); end-of-iter barrier is
// lgkmcnt-only (s_barrier) so the P global-stores drain under the NEXT
// iteration's staging-load wait instead of being exposed (R3 paid vmcnt(0)
// on stores every K-step).
// ---------------------------------------------------------------------------
#define BM 128
#define BN 128
#define BK 32

enum GemmMode { MODE_PROJ = 0, MODE_QK = 1, MODE_PV = 2, MODE_WO = 3 };

template <int MODE>
__global__ __launch_bounds__(256)
void gemm_nt(const u16* __restrict__ A, const u16* __restrict__ Bb,
             void* __restrict__ Cp, float* __restrict__ rows,
             float* __restrict__ Pout,
             int K, int lda, int ldb, int ldc, int nx)
{
  int bn, bm;
  if constexpr (MODE == MODE_QK) {
    // triangular decode: blockIdx.x = bm*(bm+1)/2 + bn, bn <= bm
    int t = blockIdx.x;
    bm = 0;
    while ((bm + 1) * (bm + 2) / 2 <= t) bm++;
    bn = t - bm * (bm + 1) / 2;
  } else if constexpr (MODE == MODE_PV) {
    bn = blockIdx.x;
    bm = (int)gridDim.y - 1 - (int)blockIdx.y;   // longest K-loops dispatch first
  } else {
    // PROJ/WO: 1D grid (gridDim.x % 8 == 0), bijective XCD swizzle (T1)
    int orig = blockIdx.x;
    int cpx  = (int)gridDim.x >> 3;
    int swz  = (orig & 7) * cpx + (orig >> 3);
    bm = swz / nx;
    bn = swz - bm * nx;
  }
  const int bz = blockIdx.z;
  const int m0 = bm * BM, n0 = bn * BN;
  const int tid = threadIdx.x;

  const u16* Ap = A;
  const u16* Bp = Bb;
  float* Cf = (float*)Cp;
  u16*   Cu = (u16*)Cp;
  float* Pp = Pout;

  if constexpr (MODE == MODE_QK) {
    Ap   += (size_t)bz * S_ * D_;           // Q slab (b,h)
    Bp   += (size_t)(bz >> 3) * S_ * D_;    // K slab (b)
    Cu   += (size_t)bz * S_ * S_;           // E slab (bf16, unnormalized exp)
    rows += (size_t)bz * S_;
  } else if constexpr (MODE == MODE_PV) {
    Ap   += (size_t)bz * S_ * S_;           // E slab (bf16)
    Bp   += (size_t)(bz >> 3) * D_ * S_;    // V^T slab (b)
    Cu   += (size_t)(bz >> 3) * S_ * (NH_ * D_) + (size_t)(bz & 7) * D_;
    rows += (size_t)bz * S_;
    Pp   += (size_t)bz * S_ * S_;           // P slab (fp32 attn_weights)
  }

  int Keff = K;
  if constexpr (MODE == MODE_PV) {          // E[m][k]==0 for k>m
    int lim = (bm + 1) * BM;
    Keff = lim < K ? lim : K;
  }

  // one shared pool: K-loop uses As|Bs; epilogue reuses it as Cs / Cs32
  __shared__ __align__(16) u16 smem[BM * BK + BN * BK + 512];
  u16* As = smem;
  u16* Bs = smem + BM * BK;
  __shared__ float invs[BM];                // PV: 1/rowsum for this row band

  const int lane = tid & 63;
  const int quad = lane >> 4;
  const int l16  = lane & 15;
  const int wave = tid >> 6;
  const int wm   = (wave >> 1) << 6;
  const int wn   = (wave & 1) << 6;

  if constexpr (MODE == MODE_PV) {
    if (tid < BM) invs[tid] = 1.0f / rows[m0 + tid];
  }

  f32x4 acc[4][4] = {};

  for (int kt = 0; kt < Keff; kt += BK) {
    #pragma unroll
    for (int i = 0; i < 2; i++) {
      int c = tid + i * 256;                // chunk id; lanes consecutive in LDS
      gld_lds16(Ap + (size_t)(m0 + (c >> 2)) * lda + kt + (c & 3) * 8, &As[c * 8]);
    }
    #pragma unroll
    for (int i = 0; i < 2; i++) {
      int c = tid + i * 256;
      gld_lds16(Bp + (size_t)(n0 + (c >> 2)) * ldb + kt + (c & 3) * 8, &Bs[c * 8]);
    }
    __syncthreads();                        // drains vmcnt(0): staging loads AND
                                            // prior-iter P stores (hidden here)

    bf16x8 af[4], bfr[4];
    #pragma unroll
    for (int i = 0; i < 4; i++)
      af[i] = *(const bf16x8*)(&As[(wm + i * 16 + l16) * BK + quad * 8]);
    #pragma unroll
    for (int j = 0; j < 4; j++)
      bfr[j] = *(const bf16x8*)(&Bs[(wn + j * 16 + l16) * BK + quad * 8]);
    #pragma unroll
    for (int i = 0; i < 4; i++)
      #pragma unroll
      for (int j = 0; j < 4; j++)
        acc[i][j] = __builtin_amdgcn_mfma_f32_16x16x32_bf16(af[i], bfr[j], acc[i][j], 0, 0, 0);

    if constexpr (MODE == MODE_PV) {
      // fused P-write: P[m][kt..kt+32) = bf2f(E_tile) * inv(rowsum[m]) (fp32)
      if (bn == 0) {
        const int r8 = tid >> 3;            // 0..31
        const int c8 = tid & 7;             // 8 float4s span the 32 cols
        #pragma unroll
        for (int rr = 0; rr < BM; rr += 32) {
          const int r = rr + r8;
          uint2v u = *(const uint2v*)(&As[r * BK + c8 * 4]);  // ds_read_b64
          const float inv = invs[r];
          float4 o;
          o.x = bf2f(u.x & 0xffff) * inv; o.y = bf2f(u.x >> 16) * inv;
          o.z = bf2f(u.y & 0xffff) * inv; o.w = bf2f(u.y >> 16) * inv;
          *(float4*)(Pp + (size_t)(m0 + r) * S_ + kt + c8 * 4) = o;
        }
      }
      // lgkmcnt-only barrier: LDS reads must complete before next staging,
      // but P global-stores need no ordering here (they drain at next
      // __syncthreads, hidden under the staging-load wait).
      asm volatile("s_waitcnt lgkmcnt(0)\n\ts_barrier" ::: "memory");
    } else {
      __syncthreads();
    }
  }

  if constexpr (MODE == MODE_PV) {
    // above-diagonal zeros: cols [Keff, S_) of this row band
    if (bn == 0 && Keff < S_) {
      const int r8 = tid >> 3;
      const int c8 = tid & 7;
      const float4 z = {0.f, 0.f, 0.f, 0.f};
      #pragma unroll
      for (int rr = 0; rr < BM; rr += 32) {
        float* pr = Pp + (size_t)(m0 + rr + r8) * S_;
        for (int c4 = (Keff >> 2) + c8; c4 < (S_ >> 2); c4 += 8)
          *(float4*)(pr + c4 * 4) = z;
      }
    }
  }

  // ---- epilogue ----
  const float SCL2 = 0.0625f * 1.44269504088896340736f;  // D^-0.5 * log2(e)
  if constexpr (MODE == MODE_WO) {
    // fp32 output: LDS repack -> float4 coalesced stores. 32 rows x 132 floats.
    float (*Cs32)[132] = (float (*)[132])smem;
    const int band16 = (wave >> 1) * 16;
    #pragma unroll
    for (int i = 0; i < 4; i++) {
      #pragma unroll
      for (int r = 0; r < 4; r++) {
        const int lr = band16 + quad * 4 + r;
        #pragma unroll
        for (int j = 0; j < 4; j++)
          Cs32[lr][wn + j * 16 + l16] = acc[i][j][r];
      }
      __syncthreads();
      #pragma unroll
      for (int ch = tid; ch < 1024; ch += 256) {
        const int rr = ch >> 5, cc = ch & 31;
        const int mg = m0 + ((rr >> 4) << 6) + i * 16 + (rr & 15);
        *(float4*)(Cf + (size_t)mg * ldc + n0 + cc * 4) =
            *(const float4*)(&Cs32[rr][cc * 4]);
      }
      __syncthreads();
    }
  } else {
    // bf16 outputs: LDS repack -> 16B/lane coalesced stores.
    u16 (*Cs)[136] = (u16 (*)[136])smem;
    const int band16 = (wave >> 1) * 16;
    #pragma unroll
    for (int i = 0; i < 4; i++) {
      #pragma unroll
      for (int r = 0; r < 4; r++) {
        const int lr = band16 + quad * 4 + r;
        const int m  = m0 + wm + i * 16 + quad * 4 + r;
        if constexpr (MODE == MODE_QK) {
          float rs = 0.f;
          #pragma unroll
          for (int j = 0; j < 4; j++) {
            int n = n0 + wn + j * 16 + l16;
            float e = (n <= m) ? exp2f(acc[i][j][r] * SCL2) : 0.f;
            rs += e;
            Cs[lr][wn + j * 16 + l16] = f2bf(e);
          }
          #pragma unroll
          for (int o = 1; o < 16; o <<= 1) rs += __shfl_xor(rs, o, 64);
          if (l16 == 0) atomicAdd(&rows[m], rs);
        } else if constexpr (MODE == MODE_PV) {
          const float inv = invs[wm + i * 16 + quad * 4 + r];
          #pragma unroll
          for (int j = 0; j < 4; j++)
            Cs[lr][wn + j * 16 + l16] = f2bf(acc[i][j][r] * inv);
        } else {
          #pragma unroll
          for (int j = 0; j < 4; j++)
            Cs[lr][wn + j * 16 + l16] = f2bf(acc[i][j][r]);
        }
      }
      __syncthreads();
      #pragma unroll
      for (int ch = tid; ch < 512; ch += 256) {
        const int rr = ch >> 4, cc = ch & 15;
        const int mg = m0 + ((rr >> 4) << 6) + i * 16 + (rr & 15);
        *(uint4v*)(Cu + (size_t)mg * ldc + n0 + cc * 8) =
            *(const uint4v*)(&Cs[rr][cc * 8]);
      }
      __syncthreads();
    }
  }
}

// ---------------------------------------------------------------------------
// Merged prep: 4x transpose_convert (Wq|Wk|Wv -> WT packed, Wo -> WoT) +
// X fp32 -> bf16 convert + Rows zero-fill.  Flat block decode.
// ---------------------------------------------------------------------------
__device__ __forceinline__ void tc_tile(const float* __restrict__ src,
                                        u16* __restrict__ dst, int K, int N,
                                        int n0, int k0, float (*t)[33])
{
  int c = threadIdx.x & 31, r = threadIdx.x >> 5;
  #pragma unroll
  for (int rr = 0; rr < 32; rr += 8)
    t[r + rr][c] = src[(size_t)(k0 + r + rr) * N + n0 + c];
  __syncthreads();
  #pragma unroll
  for (int rr = 0; rr < 32; rr += 8)
    dst[(size_t)(n0 + r + rr) * K + k0 + c] = f2bf(t[c][r + rr]);
}

__global__ __launch_bounds__(256)
void prep_kernel(const float* __restrict__ X,
                 const float* __restrict__ Wq, const float* __restrict__ Wk,
                 const float* __restrict__ Wv, const float* __restrict__ Wo,
                 u16* __restrict__ Xbf, u16* __restrict__ WT,
                 u16* __restrict__ WoT, float* __restrict__ Rows)
{
  __shared__ float t[32][33];
  const int bid = blockIdx.x;
  if (bid < 4096) {                                   // Wq: 64x64 tiles
    tc_tile(Wq, WT, 2048, 2048, (bid & 63) * 32, (bid >> 6) * 32, t);
  } else if (bid < 4608) {                            // Wk: 8x64 tiles
    int l = bid - 4096;
    tc_tile(Wk, WT + 2048 * 2048, 2048, 256, (l & 7) * 32, (l >> 3) * 32, t);
  } else if (bid < 5120) {                            // Wv: 8x64 tiles
    int l = bid - 4608;
    tc_tile(Wv, WT + 2304 * 2048, 2048, 256, (l & 7) * 32, (l >> 3) * 32, t);
  } else if (bid < 9216) {                            // Wo: 64x64 tiles
    int l = bid - 5120;
    tc_tile(Wo, WoT, 2048, 2048, (l & 63) * 32, (l >> 6) * 32, t);
  } else if (bid < 11264) {                           // X fp32 -> bf16
    int l = bid - 9216;                               // 0..2047
    #pragma unroll
    for (int it = 0; it < 4; ++it) {
      int i = it * 524288 + l * 256 + threadIdx.x;
      float4 f = ((const float4*)X)[i];
      uint2v p;
      p.x = (unsigned)f2bf(f.x) | ((unsigned)f2bf(f.y) << 16);
      p.y = (unsigned)f2bf(f.z) | ((unsigned)f2bf(f.w) << 16);
      ((uint2v*)Xbf)[i] = p;
    }
  } else {                                            // zero Rows (8 blocks)
    int l = bid - 11264;
    const float4 z = {0.f, 0.f, 0.f, 0.f};
    #pragma unroll
    for (int it = 0; it < 4; ++it)
      ((float4*)Rows)[it * 2048 + l * 256 + threadIdx.x] = z;
  }
}

// ---------------------------------------------------------------------------
// Merged post-projection: RoPE-Q, RoPE-K (16B vectorized), V-transpose.
// RoPE handles (d, d+128) pairs; cos[d+128]==cos[d] (emb = concat(freqs,freqs)).
// ---------------------------------------------------------------------------
__global__ __launch_bounds__(256)
void postproj_kernel(const u16* __restrict__ raw, const float* __restrict__ cosb,
                     const float* __restrict__ sinb, u16* __restrict__ qout,
                     u16* __restrict__ kout, u16* __restrict__ vt)
{
  __shared__ u16 t[32][34];
  const int bid = blockIdx.x;
  if (bid < 1024) {                                   // RoPE Q (vectorized)
    const int row = threadIdx.x >> 4;                 // 0..15
    const int d8  = (threadIdx.x & 15) * 8;           // 0..120
    #pragma unroll
    for (int it2 = 0; it2 < 2; ++it2) {
      int idx = bid * 32 + it2 * 16 + row;            // (bs*NH + h) in [0, 32768)
      int h = idx & 7, bs = idx >> 3;
      int b = bs >> 11, s = bs & (S_ - 1);
      size_t base = (size_t)bs * 2560 + (size_t)h * D_;
      uint4v u1 = *(const uint4v*)(raw + base + d8);
      uint4v u2 = *(const uint4v*)(raw + base + 128 + d8);
      float4 c0 = *(const float4*)(cosb + (size_t)bs * D_ + d8);
      float4 c1 = *(const float4*)(cosb + (size_t)bs * D_ + d8 + 4);
      float4 s0 = *(const float4*)(sinb + (size_t)bs * D_ + d8);
      float4 s1 = *(const float4*)(sinb + (size_t)bs * D_ + d8 + 4);
      float a[8], bq[8], cc[8], ss[8], r1[8], r2[8];
      bf8_unpack(u1, a); bf8_unpack(u2, bq);
      cc[0]=c0.x; cc[1]=c0.y; cc[2]=c0.z; cc[3]=c0.w;
      cc[4]=c1.x; cc[5]=c1.y; cc[6]=c1.z; cc[7]=c1.w;
      ss[0]=s0.x; ss[1]=s0.y; ss[2]=s0.z; ss[3]=s0.w;
      ss[4]=s1.x; ss[5]=s1.y; ss[6]=s1.z; ss[7]=s1.w;
      #pragma unroll
      for (int i = 0; i < 8; ++i) {
        r1[i] = a[i] * cc[i] - bq[i] * ss[i];
        r2[i] = bq[i] * cc[i] + a[i] * ss[i];
      }
      size_t ob = (((size_t)b * NH_ + h) * S_ + s) * D_;
      *(uint4v*)(qout + ob + d8)       = bf8_pack(r1);
      *(uint4v*)(qout + ob + 128 + d8) = bf8_pack(r2);
    }
  } else if (bid < 1280) {                            // RoPE K (vectorized)
    const int l   = bid - 1024;                       // 0..255
    const int row = threadIdx.x >> 4;                 // 0..15
    const int d8  = (threadIdx.x & 15) * 8;
    int bs = l * 16 + row;                            // in [0, 4096)
    size_t base = (size_t)bs * 2560 + 2048;
    uint4v u1 = *(const uint4v*)(raw + base + d8);
    uint4v u2 = *(const uint4v*)(raw + base + 128 + d8);
    float4 c0 = *(const float4*)(cosb + (size_t)bs * D_ + d8);
    float4 c1 = *(const float4*)(cosb + (size_t)bs * D_ + d8 + 4);
    float4 s0 = *(const float4*)(sinb + (size_t)bs * D_ + d8);
    float4 s1 = *(const float4*)(sinb + (size_t)bs * D_ + d8 + 4);
    float a[8], bq[8], cc[8], ss[8], r1[8], r2[8];
    bf8_unpack(u1, a); bf8_unpack(u2, bq);
    cc[0]=c0.x; cc[1]=c0.y; cc[2]=c0.z; cc[3]=c0.w;
    cc[4]=c1.x; cc[5]=c1.y; cc[6]=c1.z; cc[7]=c1.w;
    ss[0]=s0.x; ss[1]=s0.y; ss[2]=s0.z; ss[3]=s0.w;
    ss[4]=s1.x; ss[5]=s1.y; ss[6]=s1.z; ss[7]=s1.w;
    #pragma unroll
    for (int i = 0; i < 8; ++i) {
      r1[i] = a[i] * cc[i] - bq[i] * ss[i];
      r2[i] = bq[i] * cc[i] + a[i] * ss[i];
    }
    *(uint4v*)(kout + (size_t)bs * D_ + d8)       = bf8_pack(r1);
    *(uint4v*)(kout + (size_t)bs * D_ + 128 + d8) = bf8_pack(r2);
  } else {                                            // V transpose -> (B,D,S)
    int l = bid - 1280;                               // 0..1023
    int b = l >> 9, rem = l & 511;
    int d0 = (rem & 7) * 32, s0 = (rem >> 3) * 32;
    int c = threadIdx.x & 31, r = threadIdx.x >> 5;
    #pragma unroll
    for (int rr = 0; rr < 32; rr += 8)
      t[r + rr][c] = raw[(size_t)(b * S_ + s0 + r + rr) * 2560 + 2304 + d0 + c];
    __syncthreads();
    #pragma unroll
    for (int rr = 0; rr < 32; rr += 8)
      vt[(size_t)b * D_ * S_ + (size_t)(d0 + r + rr) * S_ + s0 + c] = t[c][r + rr];
  }
}

// ---------------------------------------------------------------------------
extern "C" void kernel_launch(void* const* d_in, const int* in_sizes, int n_in,
                              void* d_out, int out_size, void* d_ws, size_t ws_size,
                              hipStream_t stream)
{
  const float* X    = (const float*)d_in[0];
  const float* cosb = (const float*)d_in[1];
  const float* sinb = (const float*)d_in[2];
  // d_in[3] = attention_mask (pure causal; synthesized in-kernel)
  const float* Wq   = (const float*)d_in[4];
  const float* Wk   = (const float*)d_in[5];
  const float* Wv   = (const float*)d_in[6];
  const float* Wo   = (const float*)d_in[7];

  float* outO = (float*)d_out;                               // (B,S,H) fp32
  float* outP = outO + (size_t)B_ * S_ * H_;                 // (B,NH,S,S) fp32

  // workspace layout (u16 elems), no aliasing (~229 MB total)
  u16* ws     = (u16*)d_ws;
  u16* Xbf    = ws;                          //  8,388,608  X bf16 (B*S, H)
  u16* WT     = Xbf    + 8388608;            //  5,242,880  packed [Wq|Wk|Wv]^T (2560,2048)
  u16* WoT    = WT     + 5242880;            //  4,194,304  Wo^T (2048,2048)
  u16* QKVraw = WoT    + 4194304;            // 10,485,760  X@W (B*S, 2560)
  u16* Qbf    = QKVraw + 10485760;           //  8,388,608  (B,NH,S,D) post-RoPE
  u16* Kbf    = Qbf    + 8388608;            //  1,048,576  (B,S,D)   post-RoPE
  u16* VT     = Kbf    + 1048576;            //  1,048,576  (B,D,S)
  u16* AObf   = VT     + 1048576;            //  8,388,608  (B,S,NH*D)
  u16* Ebf    = AObf   + 8388608;            // 67,108,864  unnormalized exp (B,NH,S,S)
  float* Rows = (float*)(Ebf + 67108864);    //     32,768  fp32 row sums

  // 1. prep: X->bf16 + weight transposes + Rows zero (one dispatch)
  prep_kernel<<<11272, 256, 0, stream>>>(X, Wq, Wk, Wv, Wo, Xbf, WT, WoT, Rows);
  // 2. fused QKV projection (one GEMM, N=2560); 1D swizzled grid 640 = 32x20
  gemm_nt<MODE_PROJ><<<640, 256, 0, stream>>>(
      Xbf, WT, QKVraw, nullptr, nullptr, 2048, 2048, 2048, 2560, 20);
  // 3. RoPE Q/K + V transpose (one dispatch)
  postproj_kernel<<<2304, 256, 0, stream>>>(QKVraw, cosb, sinb, Qbf, Kbf, VT);
  // 4. E = exp(QK^T * scale) bf16 (lower-tri tiles only), rowsums via atomics
  gemm_nt<MODE_QK><<<dim3(136, 1, 16), 256, 0, stream>>>(
      Qbf, Kbf, Ebf, Rows, nullptr, 256, 256, 256, 2048, 0);
  // 5. attn_out = (E @ V) * inv(rowsum) + fused P = E * inv(rowsum) (fp32)
  gemm_nt<MODE_PV><<<dim3(2, 16, 16), 256, 0, stream>>>(
      Ebf, VT, AObf, Rows, outP, 2048, 2048, 2048, 2048, 0);
  // 6. @ Wo -> fp32 attn_output; 1D swizzled grid 512 = 32x16
  gemm_nt<MODE_WO><<<512, 256, 0, stream>>>(
      AObf, WoT, outO, nullptr, nullptr, 2048, 2048, 2048, 2048, 16);
}